// Round 7
// baseline (195.833 us; speedup 1.0000x reference)
//
#include <hip/hip_runtime.h>

// ---------------------------------------------------------------------------
// Causal MHSA. B=2, T=2048, D=1024, H=16, hd=64. fp32 in -> bf16 internal ->
// fp32 out. R7: attention computes S^T and O^T so all LDS writes are packed
// (b64/b128, conflict-floor); V is stored pre-transposed [B,H,hd,T] by the
// QKV GEMM epilogue; gemm_out uses 128x64 tiles (512 blocks, 2/CU).
// ---------------------------------------------------------------------------

#define T_SEQ 2048
#define D_MODEL 1024
#define NEG_BIG (-1.0e30f)
#define Q_SCALE 0.18033688f   // 0.125 * log2(e): attention uses exp2 directly

typedef float f32x4 __attribute__((ext_vector_type(4)));
typedef short s16x8 __attribute__((ext_vector_type(8)));
typedef __bf16 bf16x8 __attribute__((ext_vector_type(8)));

__device__ __forceinline__ f32x4 mfma16(s16x8 a, s16x8 b, f32x4 c) {
    // C[m][n] = sum_k A[m][k]*B[n][k]; per-lane: a=A[m=l16][k=quad*8+j],
    // b=B[n=l16][k=quad*8+j], C: col=l16=n, row=quad*4+r=m  (verified R4-R6)
    return __builtin_amdgcn_mfma_f32_16x16x32_bf16(
        __builtin_bit_cast(bf16x8, a), __builtin_bit_cast(bf16x8, b), c, 0, 0, 0);
}

__device__ __forceinline__ short f2bf(float f) {          // RNE
    unsigned int u = __float_as_uint(f);
    u += 0x7fffu + ((u >> 16) & 1u);
    return (short)(u >> 16);
}
__device__ __forceinline__ unsigned f2bfu(float f) {      // RNE, as unsigned
    unsigned int u = __float_as_uint(f);
    u += 0x7fffu + ((u >> 16) & 1u);
    return u >> 16;
}
__device__ __forceinline__ unsigned f2bfu_fast(float f) { // RN-away, positive
    return (__float_as_uint(f) + 0x8000u) >> 16;
}
__device__ __forceinline__ float bf2f(short s) {
    return __uint_as_float(((unsigned int)(unsigned short)s) << 16);
}

// async global->LDS, 16B/lane; lds base wave-uniform
__device__ __forceinline__ void async_lds16(const short* g, short* l) {
    __builtin_amdgcn_global_load_lds(
        (const __attribute__((address_space(1))) unsigned int*)g,
        (__attribute__((address_space(3))) unsigned int*)l, 16, 0, 0);
}

// ---------------------------------------------------------------------------
// Fused canon: all five fp32 inputs -> bf16, one launch, float4-vectorized.
// ---------------------------------------------------------------------------
#define N_X   4194304
#define N_WI  3145728
#define N_BI  3072
#define N_WO  1048576
#define N_BO  1024
#define V_X   (N_X  / 4)
#define V_WI  (N_WI / 4)
#define V_BI  (N_BI / 4)
#define V_WO  (N_WO / 4)
#define V_BO  (N_BO / 4)
#define V_TOT (V_X + V_WI + V_BI + V_WO + V_BO)

__global__ __launch_bounds__(256) void canon_all_kernel(
    const float* __restrict__ x, const float* __restrict__ wi,
    const float* __restrict__ bi, const float* __restrict__ wo,
    const float* __restrict__ bo,
    short* __restrict__ xb, short* __restrict__ wib, short* __restrict__ bib,
    short* __restrict__ wob, short* __restrict__ bob)
{
    int i = blockIdx.x * 256 + threadIdx.x;
    if (i >= V_TOT) return;
    const float* src; short* dst; int off;
    if      (i < V_X)                    { src = x;  dst = xb;  off = i; }
    else if (i < V_X+V_WI)               { src = wi; dst = wib; off = i - V_X; }
    else if (i < V_X+V_WI+V_BI)          { src = bi; dst = bib; off = i - V_X - V_WI; }
    else if (i < V_X+V_WI+V_BI+V_WO)     { src = wo; dst = wob; off = i - V_X - V_WI - V_BI; }
    else                                 { src = bo; dst = bob; off = i - V_X - V_WI - V_BI - V_WO; }
    float4 v = ((const float4*)src)[off];
    short4 o = { f2bf(v.x), f2bf(v.y), f2bf(v.z), f2bf(v.w) };
    ((short4*)dst)[off] = o;
}

// ---------------------------------------------------------------------------
// GEMM1: qkv = x @ w_in^T + b_in.
//  q -> [B,H,T,64] scaled by Q_SCALE (scalar bf16 stores)
//  k -> [B,H,T,64]                  (scalar bf16 stores)
//  v -> [B,H,64,T] TRANSPOSED      (packed b64 stores: 4 consecutive t)
// ---------------------------------------------------------------------------
__global__ __launch_bounds__(256) void gemm_qkv_kernel(
    const short* __restrict__ A, const short* __restrict__ B,
    const short* __restrict__ bias,
    short* __restrict__ qo, short* __restrict__ ko, short* __restrict__ vt)
{
    const int K = 1024;
    alignas(16) __shared__ short As[128][32];
    alignas(16) __shared__ short Bs[128][32];
    const int m0 = blockIdx.x * 128;
    const int n0 = blockIdx.y * 128;
    const int tid = threadIdx.x;
    const int lane = tid & 63;
    const int w = tid >> 6;
    const int wm = (w >> 1) * 64, wn = (w & 1) * 64;
    const int quad = lane >> 4, l16 = lane & 15;

    f32x4 acc[4][4];
    const f32x4 zero = {0.f, 0.f, 0.f, 0.f};
#pragma unroll
    for (int i = 0; i < 4; ++i)
#pragma unroll
        for (int j = 0; j < 4; ++j) acc[i][j] = zero;

    const int lrow = lane >> 2;
    const int lcol = (lane & 3) * 8;
    const short* gA0 = &A[(m0 + w*32      + lrow) * K + lcol];
    const short* gA1 = &A[(m0 + w*32 + 16 + lrow) * K + lcol];
    const short* gB0 = &B[(n0 + w*32      + lrow) * K + lcol];
    const short* gB1 = &B[(n0 + w*32 + 16 + lrow) * K + lcol];
    short* lA0 = &As[w*32][0];
    short* lA1 = &As[w*32 + 16][0];
    short* lB0 = &Bs[w*32][0];
    short* lB1 = &Bs[w*32 + 16][0];

    for (int k0 = 0; k0 < K; k0 += 32) {
        __syncthreads();
        async_lds16(gA0 + k0, lA0);
        async_lds16(gA1 + k0, lA1);
        async_lds16(gB0 + k0, lB0);
        async_lds16(gB1 + k0, lB1);
        __syncthreads();

        s16x8 af[4], bfr[4];
#pragma unroll
        for (int i = 0; i < 4; ++i) af[i]  = *(const s16x8*)&As[wm + i*16 + l16][quad*8];
#pragma unroll
        for (int j = 0; j < 4; ++j) bfr[j] = *(const s16x8*)&Bs[wn + j*16 + l16][quad*8];
#pragma unroll
        for (int i = 0; i < 4; ++i)
#pragma unroll
            for (int j = 0; j < 4; ++j)
                acc[i][j] = mfma16(af[i], bfr[j], acc[i][j]);
    }

#pragma unroll
    for (int j = 0; j < 4; ++j) {
        int n = n0 + wn + j*16 + l16;
        float bi = bf2f(bias[n]);
        int which = n >> 10;
        int h = (n >> 6) & 15, d = n & 63;
        if (which == 2) {
            // transposed V: vt[((b*16+h)*64 + d)*2048 + t], pack 4 t per store
#pragma unroll
            for (int i = 0; i < 4; ++i) {
                int tb = m0 + wm + i*16 + quad*4;     // 4096 rows: b = tb>>11
                int b = tb >> 11, t = tb & 2047;
                uint2 pk;
                pk.x = f2bfu(acc[i][j][0] + bi) | (f2bfu(acc[i][j][1] + bi) << 16);
                pk.y = f2bfu(acc[i][j][2] + bi) | (f2bfu(acc[i][j][3] + bi) << 16);
                *(uint2*)&vt[(((size_t)(b*16 + h)) * 64 + d) * 2048 + t] = pk;
            }
        } else {
            short* dst = (which == 0) ? qo : ko;
            float scl = (which == 0) ? Q_SCALE : 1.0f;
#pragma unroll
            for (int i = 0; i < 4; ++i) {
#pragma unroll
                for (int r = 0; r < 4; ++r) {
                    int m = m0 + wm + i*16 + quad*4 + r;
                    int b = m >> 11, t = m & 2047;
                    float v = (acc[i][j][r] + bi) * scl;
                    dst[(((b*16 + h) * 2048) + t) * 64 + d] = f2bf(v);
                }
            }
        }
    }
}

// ---------------------------------------------------------------------------
// Flash attention v3 (S^T / O^T orientation):
//  S^T = mfma(A=K-rows, B=Q-rows): lane holds P[q=l16][s=sub*16+quad*4+r]
//   -> exp2 -> pack 4 -> ds_write_b64 into Pl[q][s]  (all-wide LDS writes)
//  O^T = mfma(A=V^T-rows from Vs, B=P-rows): lane holds O[q=l16][d=quad*4+r]
//   -> lrow is per-lane scalar (reduce over quads at end), packed b64 stores.
//  V^T comes pre-transposed from gemm_qkv; staged like K (float4 -> b128).
// ---------------------------------------------------------------------------
__global__ __launch_bounds__(256) void attn_kernel(
    const short* __restrict__ Q, const short* __restrict__ K,
    const short* __restrict__ Vt, short* __restrict__ ctx)
{
    alignas(16) __shared__ short Ks[64][72];      // [s][d]
    alignas(16) __shared__ short Vs[64][72];      // [d][s]  (V^T tile)
    alignas(16) __shared__ short Pl[4][16][72];   // per-wave [q][s]

    const int bh = blockIdx.x;
    const int qt = 31 - (int)blockIdx.y;          // heavy tiles dispatch first
    const int qbase = qt * 64;
    const int tid = threadIdx.x;
    const int w = tid >> 6, lane = tid & 63;
    const int quad = lane >> 4, l16 = lane & 15;
    const int b = bh >> 4, h = bh & 15;

    const short* Qb  = Q  + bh * T_SEQ * 64;
    const short* Kb  = K  + bh * T_SEQ * 64;
    const short* Vbt = Vt + bh * 64 * T_SEQ;      // [d][t]

    // Q B-frags: rows q = qbase + w*16 + l16
    const short* qrow = Qb + (qbase + w*16 + l16) * 64;
    const s16x8 qa0 = *(const s16x8*)(qrow + quad*8);
    const s16x8 qa1 = *(const s16x8*)(qrow + 32 + quad*8);

    const f32x4 zero = {0.f, 0.f, 0.f, 0.f};
    f32x4 o[4];                                   // O^T: d = dt*16+quad*4+r, q = l16
#pragma unroll
    for (int dt = 0; dt < 4; ++dt) o[dt] = zero;
    float lsum = 0.f;                             // row-sum for q=l16 (this wave's quads)

    const int sr  = tid >> 3;                     // 0..31
    const int scl = (tid & 7) * 8;                // 0..56
    const int qg  = qbase + w*16 + l16;           // this lane's q row

    for (int s0 = 0; s0 <= qbase; s0 += 64) {
        __syncthreads();
        // stage K [s][d] and V^T [d][s] — both plain float4 -> ds_write_b128
        *(float4*)&Ks[sr][scl]    = *(const float4*)&Kb[(s0 + sr) * 64 + scl];
        *(float4*)&Ks[sr+32][scl] = *(const float4*)&Kb[(s0 + sr + 32) * 64 + scl];
        *(float4*)&Vs[sr][scl]    = *(const float4*)&Vbt[(size_t)sr * T_SEQ + s0 + scl];
        *(float4*)&Vs[sr+32][scl] = *(const float4*)&Vbt[(size_t)(sr + 32) * T_SEQ + s0 + scl];
        __syncthreads();

        // S^T = K Q^T  (A = K rows: m = s-local, k = d)
#pragma unroll
        for (int sub = 0; sub < 4; ++sub) {
            s16x8 ka0 = *(const s16x8*)&Ks[sub*16 + l16][quad*8];
            s16x8 ka1 = *(const s16x8*)&Ks[sub*16 + l16][32 + quad*8];
            f32x4 S = mfma16(ka1, qa1, mfma16(ka0, qa0, zero));
            // causal mask (diagonal tile only): s_glob > q
            if (s0 == qbase) {
                int sb = s0 + sub*16 + quad*4;
#pragma unroll
                for (int r = 0; r < 4; ++r)
                    if (sb + r > qg) S[r] = NEG_BIG;
            }
            // exp2 (scores already in log2 units), accumulate, pack, one b64
            float p0 = exp2f(S[0]), p1 = exp2f(S[1]);
            float p2 = exp2f(S[2]), p3 = exp2f(S[3]);
            lsum += (p0 + p1) + (p2 + p3);
            uint2 pk;
            pk.x = f2bfu_fast(p0) | (f2bfu_fast(p1) << 16);
            pk.y = f2bfu_fast(p2) | (f2bfu_fast(p3) << 16);
            *(uint2*)&Pl[w][l16][sub*16 + quad*4] = pk;
        }
        // wave-private Pl: in-order within wave, no barrier

        // O^T += V^T P^T  (A = Vs rows: m = d, k = s ; B = Pl rows: n = q)
        s16x8 pb0 = *(const s16x8*)&Pl[w][l16][quad*8];
        s16x8 pb1 = *(const s16x8*)&Pl[w][l16][32 + quad*8];
#pragma unroll
        for (int dt = 0; dt < 4; ++dt) {
            s16x8 va0 = *(const s16x8*)&Vs[dt*16 + l16][quad*8];
            s16x8 va1 = *(const s16x8*)&Vs[dt*16 + l16][32 + quad*8];
            o[dt] = mfma16(va1, pb1, mfma16(va0, pb0, o[dt]));
        }
    }

    // reduce lsum over the 4 quads (lanes with same l16), normalize, store
    lsum += __shfl_xor(lsum, 16, 64);
    lsum += __shfl_xor(lsum, 32, 64);
    float inv = 1.0f / lsum;
    int base = (b * T_SEQ + qg) * D_MODEL + h * 64;
#pragma unroll
    for (int dt = 0; dt < 4; ++dt) {
        uint2 pk;
        pk.x = f2bfu(o[dt][0] * inv) | (f2bfu(o[dt][1] * inv) << 16);
        pk.y = f2bfu(o[dt][2] * inv) | (f2bfu(o[dt][3] * inv) << 16);
        *(uint2*)&ctx[base + dt*16 + quad*4] = pk;
    }
}

// ---------------------------------------------------------------------------
// GEMM2: out = ctx @ w_out^T + b_out, fp32 store. 128x64 tiles -> 512 blocks.
// ---------------------------------------------------------------------------
__global__ __launch_bounds__(256) void gemm_out_kernel(
    const short* __restrict__ A, const short* __restrict__ B,
    const short* __restrict__ bias, float* __restrict__ out)
{
    const int K = 1024;
    alignas(16) __shared__ short As[128][32];
    alignas(16) __shared__ short Bs[64][32];
    const int m0 = blockIdx.x * 128;
    const int n0 = blockIdx.y * 64;
    const int tid = threadIdx.x;
    const int lane = tid & 63;
    const int w = tid >> 6;
    const int wm = (w >> 1) * 64, wn = (w & 1) * 32;
    const int quad = lane >> 4, l16 = lane & 15;

    f32x4 acc[4][2];
    const f32x4 zero = {0.f, 0.f, 0.f, 0.f};
#pragma unroll
    for (int i = 0; i < 4; ++i)
#pragma unroll
        for (int j = 0; j < 2; ++j) acc[i][j] = zero;

    const int lrow = lane >> 2;
    const int lcol = (lane & 3) * 8;
    const short* gA0 = &A[(m0 + w*32      + lrow) * K + lcol];
    const short* gA1 = &A[(m0 + w*32 + 16 + lrow) * K + lcol];
    const short* gB0 = &B[(n0 + w*16      + lrow) * K + lcol];
    short* lA0 = &As[w*32][0];
    short* lA1 = &As[w*32 + 16][0];
    short* lB0 = &Bs[w*16][0];

    for (int k0 = 0; k0 < K; k0 += 32) {
        __syncthreads();
        async_lds16(gA0 + k0, lA0);
        async_lds16(gA1 + k0, lA1);
        async_lds16(gB0 + k0, lB0);
        __syncthreads();

        s16x8 af[4], bfr[2];
#pragma unroll
        for (int i = 0; i < 4; ++i) af[i]  = *(const s16x8*)&As[wm + i*16 + l16][quad*8];
#pragma unroll
        for (int j = 0; j < 2; ++j) bfr[j] = *(const s16x8*)&Bs[wn + j*16 + l16][quad*8];
#pragma unroll
        for (int i = 0; i < 4; ++i)
#pragma unroll
            for (int j = 0; j < 2; ++j)
                acc[i][j] = mfma16(af[i], bfr[j], acc[i][j]);
    }

#pragma unroll
    for (int j = 0; j < 2; ++j) {
        int n = n0 + wn + j*16 + l16;
        float bi = bf2f(bias[n]);
#pragma unroll
        for (int i = 0; i < 4; ++i) {
#pragma unroll
            for (int r = 0; r < 4; ++r) {
                int m = m0 + wm + i*16 + quad*4 + r;
                out[m * 1024 + n] = acc[i][j][r] + bi;
            }
        }
    }
}

// ---------------------------------------------------------------------------
extern "C" void kernel_launch(void* const* d_in, const int* in_sizes, int n_in,
                              void* d_out, int out_size, void* d_ws, size_t ws_size,
                              hipStream_t stream) {
    float* out = (float*)d_out;
    char* ws = (char*)d_ws;

    const size_t MB = 1u << 20;
    short* xb     = (short*)(ws);            // 8 MB
    short* w_inb  = (short*)(ws + 8*MB);     // 6 MB
    short* b_inb  = (short*)(ws + 14*MB);    // 6 KB
    short* w_outb = (short*)(ws + 15*MB);    // 2 MB
    short* b_outb = (short*)(ws + 17*MB);    // 2 KB
    short* qb     = (short*)(ws + 18*MB);    // 8 MB  [B,H,T,64]
    short* kb     = (short*)(ws + 26*MB);    // 8 MB  [B,H,T,64]
    short* vtb    = (short*)(ws + 34*MB);    // 8 MB  [B,H,64,T]  (transposed)
    short* ctxb   = (short*)(ws + 42*MB);    // 8 MB  [B,T,D]

    canon_all_kernel<<<(V_TOT + 255) / 256, 256, 0, stream>>>(
        (const float*)d_in[0], (const float*)d_in[1], (const float*)d_in[2],
        (const float*)d_in[3], (const float*)d_in[4],
        xb, w_inb, b_inb, w_outb, b_outb);

    gemm_qkv_kernel<<<dim3(32, 24), 256, 0, stream>>>(xb, w_inb, b_inb, qb, kb, vtb);
    attn_kernel<<<dim3(32, 32), 256, 0, stream>>>(qb, kb, vtb, ctxb);
    gemm_out_kernel<<<dim3(32, 16), 256, 0, stream>>>(ctxb, w_outb, b_outb, out);
}